// Round 4
// baseline (778.203 us; speedup 1.0000x reference)
//
#include <hip/hip_runtime.h>

typedef _Float16 f16;
typedef _Float16 f16x4 __attribute__((ext_vector_type(4)));
typedef _Float16 f16x8 __attribute__((ext_vector_type(8)));
typedef float f32x4 __attribute__((ext_vector_type(4)));

#define T_STEPS 25
#define BATCH   4096
#define DIN     784
#define DH      1000
#define HP      1024
#define DOUT    10
#define MROWS   (T_STEPS * BATCH)   // 102400
#define KSEG    800                 // 784 padded to 800 (25 * 32)
#define KA      (2 * KSEG)          // A width: [xhi | xlo] = 1600
#define KB      (3 * KSEG)          // B width: [whi | whi | wlo] = 2400
#define NTILES  (KB / 32)           // 75 K-tiles of 32

// ---------------------------------------------------------------------------
// Convert X (fp32 [MROWS][784]) -> Ah f16 [MROWS][1600] = [hi(800) | lo(800)]
// ---------------------------------------------------------------------------
__global__ void aconv_kernel(const float* __restrict__ x, f16* __restrict__ Ah)
{
    const int total = MROWS * 200;
    for (int idx = blockIdx.x * blockDim.x + threadIdx.x; idx < total;
         idx += gridDim.x * blockDim.x) {
        const int r  = idx / 200;
        const int c4 = (idx - r * 200) * 4;
        f16x4 hi, lo;
        if (c4 < DIN) {
            const float4 v = *(const float4*)(x + (size_t)r * DIN + c4);
            const float vv[4] = {v.x, v.y, v.z, v.w};
            #pragma unroll
            for (int j = 0; j < 4; ++j) {
                f16 h = (f16)vv[j];
                hi[j] = h;
                lo[j] = (f16)(vv[j] - (float)h);
            }
        } else {
            #pragma unroll
            for (int j = 0; j < 4; ++j) { hi[j] = (f16)0.f; lo[j] = (f16)0.f; }
        }
        *(f16x4*)(Ah + (size_t)r * KA + c4)        = hi;
        *(f16x4*)(Ah + (size_t)r * KA + KSEG + c4) = lo;
    }
}

// ---------------------------------------------------------------------------
// Weights: Wh f16 [HP][2400] = [whi | whi | wlo]; b1p fp32; w2t fp32 [HP][10].
// ---------------------------------------------------------------------------
__global__ void wconv_kernel(const float* __restrict__ w1, const float* __restrict__ b1,
                             const float* __restrict__ w2,
                             f16* __restrict__ Wh, float* __restrict__ b1p,
                             float* __restrict__ w2t)
{
    const int stride = gridDim.x * blockDim.x;
    const int tid0 = blockIdx.x * blockDim.x + threadIdx.x;
    for (int idx = tid0; idx < HP * KB; idx += stride) {
        const int n  = idx / KB;
        const int k  = idx - n * KB;
        const int seg = k / KSEG;
        const int kc  = k - seg * KSEG;
        float w = (n < DH && kc < DIN) ? w1[n * DIN + kc] : 0.f;
        f16 h = (f16)w;
        Wh[idx] = (seg < 2) ? h : (f16)(w - (float)h);
    }
    for (int idx = tid0; idx < HP; idx += stride)
        b1p[idx] = (idx < DH) ? b1[idx] : 0.f;
    for (int idx = tid0; idx < HP * DOUT; idx += stride) {
        const int h = idx / DOUT;
        const int o = idx - h * DOUT;
        w2t[idx] = (h < DH) ? w2[o * DH + h] : 0.f;
    }
}

// ---------------------------------------------------------------------------
// 256x256-tile GEMM: cur1 = Ah @ Wh^T + b1p.
// 512 thr (8 waves 2Mx4N), BK=32, 4-deep LDS ring (128 KB).
// ONE barrier per K-tile; counted lgkmcnt(4)/lgkmcnt(0) between the two
// 16-MFMA clusters; counted vmcnt(8); setprio around MFMA; XOR swizzle
// both-sides (pre-swizzled global src for linear global_load_lds + swz read).
// Hazards: (C1) tile t+1 staged -> own vmcnt(8) + the end-of-tile barrier.
//          (C2) slot (t+3)&3 free for staging -> every wave drained its reads
//               of tile t-1 (lgkmcnt(0) before its 2nd MFMA cluster) before
//               the end-of-(t-1) barrier, which all waves passed.
// Grid: (MROWS/256) * (HP/256) = 400 * 4 = 1600 blocks (1600 % 8 == 0).
// ---------------------------------------------------------------------------
#define GL(gp, ldsoff) __builtin_amdgcn_global_load_lds( \
    (const __attribute__((address_space(1))) void*)(gp), \
    (__attribute__((address_space(3))) void*)(lds + (ldsoff)), 16, 0, 0)

#define STAGE_A(tt) do { \
    const int ak_ = (((tt) < 50) ? (tt) : ((tt) - 50)) * 32; \
    GL(Ag + ak_,            ((tt) & 3) * 8192 + widoff); \
    GL(Ag + ak_ + 128 * KA, ((tt) & 3) * 8192 + 4096 + widoff); } while (0)
#define STAGE_B(tt) do { \
    const int bk_ = (tt) * 32; \
    GL(Bg + bk_,                     32768 + ((tt) & 3) * 8192 + widoff); \
    GL(Bg + bk_ + (size_t)128 * KB,  32768 + ((tt) & 3) * 8192 + 4096 + widoff); } while (0)

#define MFMA16(A0, A1, A2, A3, M0) \
    acc[M0+0][0] = __builtin_amdgcn_mfma_f32_16x16x32_f16(A0, bf0, acc[M0+0][0], 0, 0, 0); \
    acc[M0+0][1] = __builtin_amdgcn_mfma_f32_16x16x32_f16(A0, bf1, acc[M0+0][1], 0, 0, 0); \
    acc[M0+0][2] = __builtin_amdgcn_mfma_f32_16x16x32_f16(A0, bf2, acc[M0+0][2], 0, 0, 0); \
    acc[M0+0][3] = __builtin_amdgcn_mfma_f32_16x16x32_f16(A0, bf3, acc[M0+0][3], 0, 0, 0); \
    acc[M0+1][0] = __builtin_amdgcn_mfma_f32_16x16x32_f16(A1, bf0, acc[M0+1][0], 0, 0, 0); \
    acc[M0+1][1] = __builtin_amdgcn_mfma_f32_16x16x32_f16(A1, bf1, acc[M0+1][1], 0, 0, 0); \
    acc[M0+1][2] = __builtin_amdgcn_mfma_f32_16x16x32_f16(A1, bf2, acc[M0+1][2], 0, 0, 0); \
    acc[M0+1][3] = __builtin_amdgcn_mfma_f32_16x16x32_f16(A1, bf3, acc[M0+1][3], 0, 0, 0); \
    acc[M0+2][0] = __builtin_amdgcn_mfma_f32_16x16x32_f16(A2, bf0, acc[M0+2][0], 0, 0, 0); \
    acc[M0+2][1] = __builtin_amdgcn_mfma_f32_16x16x32_f16(A2, bf1, acc[M0+2][1], 0, 0, 0); \
    acc[M0+2][2] = __builtin_amdgcn_mfma_f32_16x16x32_f16(A2, bf2, acc[M0+2][2], 0, 0, 0); \
    acc[M0+2][3] = __builtin_amdgcn_mfma_f32_16x16x32_f16(A2, bf3, acc[M0+2][3], 0, 0, 0); \
    acc[M0+3][0] = __builtin_amdgcn_mfma_f32_16x16x32_f16(A3, bf0, acc[M0+3][0], 0, 0, 0); \
    acc[M0+3][1] = __builtin_amdgcn_mfma_f32_16x16x32_f16(A3, bf1, acc[M0+3][1], 0, 0, 0); \
    acc[M0+3][2] = __builtin_amdgcn_mfma_f32_16x16x32_f16(A3, bf2, acc[M0+3][2], 0, 0, 0); \
    acc[M0+3][3] = __builtin_amdgcn_mfma_f32_16x16x32_f16(A3, bf3, acc[M0+3][3], 0, 0, 0);

// One K-tile = one phase; MFMA call order per acc identical to round 3
// (bitwise-same result; absmax != 0.03125 would flag a race).
#define BODY(tt, STG, WAITSTR) do { \
    const int bA = ((tt) & 3) * 8192; \
    const int bB = 32768 + ((tt) & 3) * 8192; \
    f16x8 af0, af1, af2, af3, af4, af5, af6, af7, bf0, bf1, bf2, bf3; \
    af0 = *(const f16x8*)(lds + bA + aoffb + 0 * 512); \
    af1 = *(const f16x8*)(lds + bA + aoffb + 1 * 512); \
    af2 = *(const f16x8*)(lds + bA + aoffb + 2 * 512); \
    af3 = *(const f16x8*)(lds + bA + aoffb + 3 * 512); \
    bf0 = *(const f16x8*)(lds + bB + boffb + 0 * 512); \
    bf1 = *(const f16x8*)(lds + bB + boffb + 1 * 512); \
    bf2 = *(const f16x8*)(lds + bB + boffb + 2 * 512); \
    bf3 = *(const f16x8*)(lds + bB + boffb + 3 * 512); \
    __builtin_amdgcn_sched_barrier(0); \
    af4 = *(const f16x8*)(lds + bA + aoffb + 4 * 512); \
    af5 = *(const f16x8*)(lds + bA + aoffb + 5 * 512); \
    af6 = *(const f16x8*)(lds + bA + aoffb + 6 * 512); \
    af7 = *(const f16x8*)(lds + bA + aoffb + 7 * 512); \
    __builtin_amdgcn_sched_barrier(0); \
    if (STG) { STAGE_A((tt) + 3); STAGE_B((tt) + 3); } \
    asm volatile("s_waitcnt lgkmcnt(4)" ::: "memory"); \
    __builtin_amdgcn_sched_barrier(0); \
    __builtin_amdgcn_s_setprio(1); \
    MFMA16(af0, af1, af2, af3, 0) \
    __builtin_amdgcn_s_setprio(0); \
    asm volatile("s_waitcnt lgkmcnt(0)" ::: "memory"); \
    __builtin_amdgcn_sched_barrier(0); \
    __builtin_amdgcn_s_setprio(1); \
    MFMA16(af4, af5, af6, af7, 4) \
    __builtin_amdgcn_s_setprio(0); \
    asm volatile(WAITSTR ::: "memory"); \
    __builtin_amdgcn_s_barrier(); \
} while (0)

__global__ __launch_bounds__(512, 2)
void gemm_kernel(const f16* __restrict__ A, const f16* __restrict__ B,
                 const float* __restrict__ bias, float* __restrict__ C)
{
    __shared__ f16 lds[65536];   // 128 KB: A ring [4][8192] | B ring at +32768

    const int bid = blockIdx.x;
    const int swz = (bid & 7) * 200 + (bid >> 3);   // bijective XCD chunking
    const int mt = swz >> 2;
    const int nt = swz & 3;
    const size_t rowBase = (size_t)mt * 256;
    const int colBase = nt * 256;

    const int tid  = threadIdx.x;
    const int wid  = tid >> 6;
    const int lane = tid & 63;
    const int wm = wid >> 2;      // 0..1
    const int wn = wid & 3;       // 0..3

    // staging source (pre-swizzled global chunk: g = chunk ^ ((row>>1)&3))
    const int srow = tid >> 2;
    const int g = (tid & 3) ^ ((tid >> 3) & 3);
    const f16* Ag = A + (rowBase + srow) * KA + g * 8;
    const f16* Bg = B + (size_t)(colBase + srow) * KB + g * 8;
    const int widoff = wid * 512;   // wave-uniform LDS base (1 KB/wave)

    // ds_read addressing (swizzled chunk, same XOR both sides)
    const int cq = (lane >> 4) ^ (((lane & 15) >> 1) & 3);
    const int aoffb = (wm * 128 + (lane & 15)) * 32 + cq * 8;
    const int boffb = (wn * 64  + (lane & 15)) * 32 + cq * 8;

    f32x4 acc[8][4];
    #pragma unroll
    for (int m = 0; m < 8; ++m)
        #pragma unroll
        for (int n = 0; n < 4; ++n)
            acc[m][n] = (f32x4){0.f, 0.f, 0.f, 0.f};

    // prologue: stage tiles 0,1,2 (12 loads in flight), land tile 0
    STAGE_A(0); STAGE_B(0);
    STAGE_A(1); STAGE_B(1);
    STAGE_A(2); STAGE_B(2);
    asm volatile("s_waitcnt vmcnt(8)" ::: "memory");
    __builtin_amdgcn_s_barrier();

    #pragma unroll 2
    for (int t = 0; t < NTILES - 3; ++t)            // t = 0..71, stage t+3
        BODY(t, 1, "s_waitcnt vmcnt(8)");
    BODY(NTILES - 3, 0, "s_waitcnt vmcnt(4)");      // t = 72: t73 lands
    BODY(NTILES - 2, 0, "s_waitcnt vmcnt(0)");      // t = 73: t74 lands
    BODY(NTILES - 1, 0, "");                        // t = 74

    // epilogue: C/D layout col = lane&15, row = (lane>>4)*4 + reg  [m89]
    const int c_col0 = colBase + wn * 64 + (lane & 15);
    const size_t c_row0 = rowBase + wm * 128 + (lane >> 4) * 4;
    #pragma unroll
    for (int n = 0; n < 4; ++n) {
        const int gcol = c_col0 + n * 16;
        const float bv = bias[gcol];
        #pragma unroll
        for (int m = 0; m < 8; ++m) {
            const size_t grow = c_row0 + m * 16;
            #pragma unroll
            for (int r = 0; r < 4; ++r)
                C[(grow + r) * HP + gcol] = acc[m][n][r] + bv;
        }
    }
}

// ---------------------------------------------------------------------------
// Temporal phase: per batch row, all 25 steps, mem1/mem2 in registers.
// ---------------------------------------------------------------------------
__global__ __launch_bounds__(256)
void phase2_kernel(const float* __restrict__ cur1, const float* __restrict__ w2t,
                   const float* __restrict__ b2, float* __restrict__ out)
{
    __shared__ float w2s[HP * DOUT];   // 40 KB
    const int tid = threadIdx.x;
    for (int i = tid; i < HP * DOUT; i += 256) w2s[i] = w2t[i];

    const int lane = tid & 63;
    const int wave = tid >> 6;
    const int b = blockIdx.x * 4 + wave;

    float m1[16];
    #pragma unroll
    for (int i = 0; i < 16; ++i) m1[i] = 0.f;
    float m2[DOUT], b2r[DOUT];
    #pragma unroll
    for (int o = 0; o < DOUT; ++o) { m2[o] = 0.f; b2r[o] = b2[o]; }
    __syncthreads();

    for (int t = 0; t < T_STEPS; ++t) {
        const float* cr = cur1 + ((size_t)t * BATCH + b) * HP;
        float p[DOUT];
        #pragma unroll
        for (int o = 0; o < DOUT; ++o) p[o] = 0.f;

        #pragma unroll
        for (int c = 0; c < 4; ++c) {
            const float4 cu = *(const float4*)(cr + c * 256 + lane * 4);
            const float cv[4] = {cu.x, cu.y, cu.z, cu.w};
            #pragma unroll
            for (int j = 0; j < 4; ++j) {
                const float mo = m1[c * 4 + j];
                const float rs = (mo > 1.0f) ? 1.0f : 0.0f;
                const float mn = 0.95f * mo + cv[j] - rs;
                m1[c * 4 + j] = mn;
                if (mn > 1.0f) {
                    const float* wr = w2s + (c * 256 + lane * 4 + j) * DOUT;
                    #pragma unroll
                    for (int o = 0; o < DOUT; ++o) p[o] += wr[o];
                }
            }
        }
        #pragma unroll
        for (int o = 0; o < DOUT; ++o) {
            float v = p[o];
            #pragma unroll
            for (int msk = 32; msk > 0; msk >>= 1) v += __shfl_xor(v, msk, 64);
            p[o] = v;
        }
        #pragma unroll
        for (int o = 0; o < DOUT; ++o) {
            const float cur2 = p[o] + b2r[o];
            const float mo = m2[o];
            const float rs = (mo > 1.0f) ? 1.0f : 0.0f;
            m2[o] = 0.95f * mo + cur2 - rs;
        }
        if (lane < DOUT)
            out[(size_t)t * (BATCH * DOUT) + (size_t)b * DOUT + lane] =
                (m2[lane] > 1.0f) ? 1.0f : 0.0f;
    }
    if (lane < DOUT)
        out[(size_t)T_STEPS * BATCH * DOUT + (size_t)b * DOUT + lane] = m2[lane];
}

// ---------------------------------------------------------------------------
extern "C" void kernel_launch(void* const* d_in, const int* in_sizes, int n_in,
                              void* d_out, int out_size, void* d_ws, size_t ws_size,
                              hipStream_t stream)
{
    const float* x  = (const float*)d_in[0];
    const float* w1 = (const float*)d_in[1];
    const float* b1 = (const float*)d_in[2];
    const float* w2 = (const float*)d_in[3];
    const float* b2 = (const float*)d_in[4];
    float* out = (float*)d_out;

    char* wsb = (char*)d_ws;
    f16*   Ah   = (f16*)(wsb);                                   // 327,680,000 B
    f16*   Wh   = (f16*)(wsb + 327680000);                       //   4,915,200 B
    float* cur1 = (float*)(wsb + 327680000 + 4915200);           // 419,430,400 B
    float* b1p  = (float*)(wsb + 327680000 + 4915200 + 419430400);
    float* w2t  = (float*)(wsb + 327680000 + 4915200 + 419430400 + 4096);

    aconv_kernel<<<4096, 256, 0, stream>>>(x, Ah);
    wconv_kernel<<<1024, 256, 0, stream>>>(w1, b1, w2, Wh, b1p, w2t);
    gemm_kernel<<<1600, 512, 0, stream>>>(Ah, Wh, b1p, cur1);
    phase2_kernel<<<1024, 256, 0, stream>>>(cur1, w2t, b2, out);
}

// Round 6
// 772.041 us; speedup vs baseline: 1.0080x; 1.0080x over previous
//
#include <hip/hip_runtime.h>

typedef _Float16 f16;
typedef _Float16 f16x4 __attribute__((ext_vector_type(4)));
typedef _Float16 f16x8 __attribute__((ext_vector_type(8)));
typedef float f32x4 __attribute__((ext_vector_type(4)));

#define T_STEPS 25
#define BATCH   4096
#define DIN     784
#define DH      1000
#define HP      1024
#define DOUT    10
#define MROWS   (T_STEPS * BATCH)   // 102400
#define KSEG    800                 // 784 padded to 800 (25 * 32)
#define KA      (2 * KSEG)          // A width: [xhi | xlo] = 1600
#define KB      (3 * KSEG)          // B width: [whi | whi | wlo] = 2400
#define NTILES  (KB / 32)           // 75 K-tiles of 32

// ---------------------------------------------------------------------------
// Convert X (fp32 [MROWS][784]) -> Ah f16 [MROWS][1600] = [hi(800) | lo(800)]
// ---------------------------------------------------------------------------
__global__ void aconv_kernel(const float* __restrict__ x, f16* __restrict__ Ah)
{
    const int total = MROWS * 200;
    for (int idx = blockIdx.x * blockDim.x + threadIdx.x; idx < total;
         idx += gridDim.x * blockDim.x) {
        const int r  = idx / 200;
        const int c4 = (idx - r * 200) * 4;
        f16x4 hi, lo;
        if (c4 < DIN) {
            const float4 v = *(const float4*)(x + (size_t)r * DIN + c4);
            const float vv[4] = {v.x, v.y, v.z, v.w};
            #pragma unroll
            for (int j = 0; j < 4; ++j) {
                f16 h = (f16)vv[j];
                hi[j] = h;
                lo[j] = (f16)(vv[j] - (float)h);
            }
        } else {
            #pragma unroll
            for (int j = 0; j < 4; ++j) { hi[j] = (f16)0.f; lo[j] = (f16)0.f; }
        }
        *(f16x4*)(Ah + (size_t)r * KA + c4)        = hi;
        *(f16x4*)(Ah + (size_t)r * KA + KSEG + c4) = lo;
    }
}

// ---------------------------------------------------------------------------
// Weights: Wh f16 [HP][2400] = [whi | whi | wlo]; b1p fp32; w2t fp32 [HP][10].
// ---------------------------------------------------------------------------
__global__ void wconv_kernel(const float* __restrict__ w1, const float* __restrict__ b1,
                             const float* __restrict__ w2,
                             f16* __restrict__ Wh, float* __restrict__ b1p,
                             float* __restrict__ w2t)
{
    const int stride = gridDim.x * blockDim.x;
    const int tid0 = blockIdx.x * blockDim.x + threadIdx.x;
    for (int idx = tid0; idx < HP * KB; idx += stride) {
        const int n  = idx / KB;
        const int k  = idx - n * KB;
        const int seg = k / KSEG;
        const int kc  = k - seg * KSEG;
        float w = (n < DH && kc < DIN) ? w1[n * DIN + kc] : 0.f;
        f16 h = (f16)w;
        Wh[idx] = (seg < 2) ? h : (f16)(w - (float)h);
    }
    for (int idx = tid0; idx < HP; idx += stride)
        b1p[idx] = (idx < DH) ? b1[idx] : 0.f;
    for (int idx = tid0; idx < HP * DOUT; idx += stride) {
        const int h = idx / DOUT;
        const int o = idx - h * DOUT;
        w2t[idx] = (h < DH) ? w2[o * DH + h] : 0.f;
    }
}

// ---------------------------------------------------------------------------
// 256x256-tile GEMM: cur1 = Ah @ Wh^T + b1p.
// 512 thr (8 waves 2Mx4N), BK=32, 4-deep LDS ring (128 KB).
// Software-pipelined LDS reads: mh1 frags load under MFMA(mh0); next tile's
// mh0+B frags load under MFMA(mh1). One barrier per tile, counted vmcnt(8).
// Hazards: (C1) tile t+1 staged -> vmcnt(8) (<=12 outstanding) + barrier.
//          (C2) slot (t+3)&3 = (t-1)&3 free: every wave lgkm-drained all its
//               tile-(t-1) reads before the barrier in BODY(t-1); STAGE(t+3)
//               is issued after that barrier.
// MFMA order per accumulator identical to rounds 3/4 -> bitwise-same C.
// Grid: (MROWS/256) * (HP/256) = 400 * 4 = 1600 blocks (1600 % 8 == 0).
// ---------------------------------------------------------------------------
#define GL(gp, ldsoff) __builtin_amdgcn_global_load_lds( \
    (const __attribute__((address_space(1))) void*)(gp), \
    (__attribute__((address_space(3))) void*)(lds + (ldsoff)), 16, 0, 0)

#define STAGE_A(tt) do { \
    const int ak_ = (((tt) < 50) ? (tt) : ((tt) - 50)) * 32; \
    GL(Ag + ak_,            ((tt) & 3) * 8192 + widoff); \
    GL(Ag + ak_ + 128 * KA, ((tt) & 3) * 8192 + 4096 + widoff); } while (0)
#define STAGE_B(tt) do { \
    const int bk_ = (tt) * 32; \
    GL(Bg + bk_,                     32768 + ((tt) & 3) * 8192 + widoff); \
    GL(Bg + bk_ + (size_t)128 * KB,  32768 + ((tt) & 3) * 8192 + 4096 + widoff); } while (0)

#define MFMA16(A0, A1, A2, A3, B0, B1, B2, B3, M0) \
    acc[M0+0][0] = __builtin_amdgcn_mfma_f32_16x16x32_f16(A0, B0, acc[M0+0][0], 0, 0, 0); \
    acc[M0+0][1] = __builtin_amdgcn_mfma_f32_16x16x32_f16(A0, B1, acc[M0+0][1], 0, 0, 0); \
    acc[M0+0][2] = __builtin_amdgcn_mfma_f32_16x16x32_f16(A0, B2, acc[M0+0][2], 0, 0, 0); \
    acc[M0+0][3] = __builtin_amdgcn_mfma_f32_16x16x32_f16(A0, B3, acc[M0+0][3], 0, 0, 0); \
    acc[M0+1][0] = __builtin_amdgcn_mfma_f32_16x16x32_f16(A1, B0, acc[M0+1][0], 0, 0, 0); \
    acc[M0+1][1] = __builtin_amdgcn_mfma_f32_16x16x32_f16(A1, B1, acc[M0+1][1], 0, 0, 0); \
    acc[M0+1][2] = __builtin_amdgcn_mfma_f32_16x16x32_f16(A1, B2, acc[M0+1][2], 0, 0, 0); \
    acc[M0+1][3] = __builtin_amdgcn_mfma_f32_16x16x32_f16(A1, B3, acc[M0+1][3], 0, 0, 0); \
    acc[M0+2][0] = __builtin_amdgcn_mfma_f32_16x16x32_f16(A2, B0, acc[M0+2][0], 0, 0, 0); \
    acc[M0+2][1] = __builtin_amdgcn_mfma_f32_16x16x32_f16(A2, B1, acc[M0+2][1], 0, 0, 0); \
    acc[M0+2][2] = __builtin_amdgcn_mfma_f32_16x16x32_f16(A2, B2, acc[M0+2][2], 0, 0, 0); \
    acc[M0+2][3] = __builtin_amdgcn_mfma_f32_16x16x32_f16(A2, B3, acc[M0+2][3], 0, 0, 0); \
    acc[M0+3][0] = __builtin_amdgcn_mfma_f32_16x16x32_f16(A3, B0, acc[M0+3][0], 0, 0, 0); \
    acc[M0+3][1] = __builtin_amdgcn_mfma_f32_16x16x32_f16(A3, B1, acc[M0+3][1], 0, 0, 0); \
    acc[M0+3][2] = __builtin_amdgcn_mfma_f32_16x16x32_f16(A3, B2, acc[M0+3][2], 0, 0, 0); \
    acc[M0+3][3] = __builtin_amdgcn_mfma_f32_16x16x32_f16(A3, B3, acc[M0+3][3], 0, 0, 0);

// One K-tile. In: aI*/bI* hold tile tt's mh0 A-frags + B-frags (in lgkm flight).
// Out: aO*/bO* hold tile tt+1's mh0 A-frags + B-frags (in lgkm flight).
#define BODY(tt, aI0,aI1,aI2,aI3, bI0,bI1,bI2,bI3, aO0,aO1,aO2,aO3, bO0,bO1,bO2,bO3, STG, VMWSTR) do { \
    const int bcur = ((tt) & 3) * 8192; \
    const int bnxt = (((tt) + 1) & 3) * 8192; \
    if (STG) { STAGE_A((tt) + 3); STAGE_B((tt) + 3); } \
    asm volatile("s_waitcnt lgkmcnt(0)" ::: "memory");   /* aI,bI landed */ \
    __builtin_amdgcn_sched_barrier(0); \
    ah0 = *(const f16x8*)(lds + bcur + aoffb + 4 * 512); \
    ah1 = *(const f16x8*)(lds + bcur + aoffb + 5 * 512); \
    ah2 = *(const f16x8*)(lds + bcur + aoffb + 6 * 512); \
    ah3 = *(const f16x8*)(lds + bcur + aoffb + 7 * 512); \
    __builtin_amdgcn_sched_barrier(0); \
    __builtin_amdgcn_s_setprio(1); \
    MFMA16(aI0, aI1, aI2, aI3, bI0, bI1, bI2, bI3, 0)    /* hides ah reads */ \
    __builtin_amdgcn_s_setprio(0); \
    asm volatile("s_waitcnt lgkmcnt(0)" ::: "memory");   /* ah landed */ \
    __builtin_amdgcn_sched_barrier(0); \
    asm volatile(VMWSTR ::: "memory"); \
    __builtin_amdgcn_s_barrier();                        /* t+1 visible; slot free */ \
    aO0 = *(const f16x8*)(lds + bnxt + aoffb + 0 * 512); \
    aO1 = *(const f16x8*)(lds + bnxt + aoffb + 1 * 512); \
    aO2 = *(const f16x8*)(lds + bnxt + aoffb + 2 * 512); \
    aO3 = *(const f16x8*)(lds + bnxt + aoffb + 3 * 512); \
    bO0 = *(const f16x8*)(lds + 32768 + bnxt + boffb + 0 * 512); \
    bO1 = *(const f16x8*)(lds + 32768 + bnxt + boffb + 1 * 512); \
    bO2 = *(const f16x8*)(lds + 32768 + bnxt + boffb + 2 * 512); \
    bO3 = *(const f16x8*)(lds + 32768 + bnxt + boffb + 3 * 512); \
    __builtin_amdgcn_sched_barrier(0); \
    __builtin_amdgcn_s_setprio(1); \
    MFMA16(ah0, ah1, ah2, ah3, bI0, bI1, bI2, bI3, 4)    /* hides aO/bO reads */ \
    __builtin_amdgcn_s_setprio(0); \
} while (0)

// Indirection so SET_A/SET_B expand into 8 args BEFORE BODY is matched.
#define BODY_(...) BODY(__VA_ARGS__)

#define SET_A aA0,aA1,aA2,aA3, bA0,bA1,bA2,bA3
#define SET_B aB0,aB1,aB2,aB3, bB0,bB1,bB2,bB3

__global__ __launch_bounds__(512, 2)
void gemm_kernel(const f16* __restrict__ A, const f16* __restrict__ B,
                 const float* __restrict__ bias, float* __restrict__ C)
{
    __shared__ f16 lds[65536];   // 128 KB: A ring [4][8192] | B ring at +32768

    const int bid = blockIdx.x;
    const int swz = (bid & 7) * 200 + (bid >> 3);   // bijective XCD chunking
    const int mt = swz >> 2;
    const int nt = swz & 3;
    const size_t rowBase = (size_t)mt * 256;
    const int colBase = nt * 256;

    const int tid  = threadIdx.x;
    const int wid  = tid >> 6;
    const int lane = tid & 63;
    const int wm = wid >> 2;      // 0..1
    const int wn = wid & 3;       // 0..3

    // staging source (pre-swizzled global chunk: g = chunk ^ ((row>>1)&3))
    const int srow = tid >> 2;
    const int g = (tid & 3) ^ ((tid >> 3) & 3);
    const f16* Ag = A + (rowBase + srow) * KA + g * 8;
    const f16* Bg = B + (size_t)(colBase + srow) * KB + g * 8;
    const int widoff = wid * 512;   // wave-uniform LDS base (1 KB/wave)

    // ds_read addressing (swizzled chunk, same XOR both sides)
    const int cq = (lane >> 4) ^ (((lane & 15) >> 1) & 3);
    const int aoffb = (wm * 128 + (lane & 15)) * 32 + cq * 8;
    const int boffb = (wn * 64  + (lane & 15)) * 32 + cq * 8;

    f32x4 acc[8][4];
    #pragma unroll
    for (int m = 0; m < 8; ++m)
        #pragma unroll
        for (int n = 0; n < 4; ++n)
            acc[m][n] = (f32x4){0.f, 0.f, 0.f, 0.f};

    f16x8 aA0, aA1, aA2, aA3, bA0, bA1, bA2, bA3;
    f16x8 aB0, aB1, aB2, aB3, bB0, bB1, bB2, bB3;
    f16x8 ah0, ah1, ah2, ah3;

    // prologue: stage tiles 0,1,2; land tile 0; issue its mh0+B reads (set A)
    STAGE_A(0); STAGE_B(0);
    STAGE_A(1); STAGE_B(1);
    STAGE_A(2); STAGE_B(2);
    asm volatile("s_waitcnt vmcnt(8)" ::: "memory");
    __builtin_amdgcn_s_barrier();
    aA0 = *(const f16x8*)(lds + aoffb + 0 * 512);
    aA1 = *(const f16x8*)(lds + aoffb + 1 * 512);
    aA2 = *(const f16x8*)(lds + aoffb + 2 * 512);
    aA3 = *(const f16x8*)(lds + aoffb + 3 * 512);
    bA0 = *(const f16x8*)(lds + 32768 + boffb + 0 * 512);
    bA1 = *(const f16x8*)(lds + 32768 + boffb + 1 * 512);
    bA2 = *(const f16x8*)(lds + 32768 + boffb + 2 * 512);
    bA3 = *(const f16x8*)(lds + 32768 + boffb + 3 * 512);

    for (int t = 0; t < NTILES - 3; t += 2) {        // t = 0..71 (72 bodies)
        BODY_(t,     SET_A, SET_B, 1, "s_waitcnt vmcnt(8)");
        BODY_(t + 1, SET_B, SET_A, 1, "s_waitcnt vmcnt(8)");
    }
    BODY_(NTILES - 3, SET_A, SET_B, 0, "s_waitcnt vmcnt(4)");   // t = 72
    BODY_(NTILES - 2, SET_B, SET_A, 0, "s_waitcnt vmcnt(0)");   // t = 73
    {   // t = 74 final: no staging, no next-tile reads, no barrier
        const int bcur = ((NTILES - 1) & 3) * 8192;
        asm volatile("s_waitcnt lgkmcnt(0)" ::: "memory");
        __builtin_amdgcn_sched_barrier(0);
        ah0 = *(const f16x8*)(lds + bcur + aoffb + 4 * 512);
        ah1 = *(const f16x8*)(lds + bcur + aoffb + 5 * 512);
        ah2 = *(const f16x8*)(lds + bcur + aoffb + 6 * 512);
        ah3 = *(const f16x8*)(lds + bcur + aoffb + 7 * 512);
        __builtin_amdgcn_sched_barrier(0);
        MFMA16(aA0, aA1, aA2, aA3, bA0, bA1, bA2, bA3, 0)
        asm volatile("s_waitcnt lgkmcnt(0)" ::: "memory");
        __builtin_amdgcn_sched_barrier(0);
        MFMA16(ah0, ah1, ah2, ah3, bA0, bA1, bA2, bA3, 4)
    }

    // epilogue: C/D layout col = lane&15, row = (lane>>4)*4 + reg  [m89]
    const int c_col0 = colBase + wn * 64 + (lane & 15);
    const size_t c_row0 = rowBase + wm * 128 + (lane >> 4) * 4;
    #pragma unroll
    for (int n = 0; n < 4; ++n) {
        const int gcol = c_col0 + n * 16;
        const float bv = bias[gcol];
        #pragma unroll
        for (int m = 0; m < 8; ++m) {
            const size_t grow = c_row0 + m * 16;
            #pragma unroll
            for (int r = 0; r < 4; ++r)
                C[(grow + r) * HP + gcol] = acc[m][n][r] + bv;
        }
    }
}

// ---------------------------------------------------------------------------
// Temporal phase: per batch row, all 25 steps, mem1/mem2 in registers.
// ---------------------------------------------------------------------------
__global__ __launch_bounds__(256)
void phase2_kernel(const float* __restrict__ cur1, const float* __restrict__ w2t,
                   const float* __restrict__ b2, float* __restrict__ out)
{
    __shared__ float w2s[HP * DOUT];   // 40 KB
    const int tid = threadIdx.x;
    for (int i = tid; i < HP * DOUT; i += 256) w2s[i] = w2t[i];

    const int lane = tid & 63;
    const int wave = tid >> 6;
    const int b = blockIdx.x * 4 + wave;

    float m1[16];
    #pragma unroll
    for (int i = 0; i < 16; ++i) m1[i] = 0.f;
    float m2[DOUT], b2r[DOUT];
    #pragma unroll
    for (int o = 0; o < DOUT; ++o) { m2[o] = 0.f; b2r[o] = b2[o]; }
    __syncthreads();

    for (int t = 0; t < T_STEPS; ++t) {
        const float* cr = cur1 + ((size_t)t * BATCH + b) * HP;
        float p[DOUT];
        #pragma unroll
        for (int o = 0; o < DOUT; ++o) p[o] = 0.f;

        #pragma unroll
        for (int c = 0; c < 4; ++c) {
            const float4 cu = *(const float4*)(cr + c * 256 + lane * 4);
            const float cv[4] = {cu.x, cu.y, cu.z, cu.w};
            #pragma unroll
            for (int j = 0; j < 4; ++j) {
                const float mo = m1[c * 4 + j];
                const float rs = (mo > 1.0f) ? 1.0f : 0.0f;
                const float mn = 0.95f * mo + cv[j] - rs;
                m1[c * 4 + j] = mn;
                if (mn > 1.0f) {
                    const float* wr = w2s + (c * 256 + lane * 4 + j) * DOUT;
                    #pragma unroll
                    for (int o = 0; o < DOUT; ++o) p[o] += wr[o];
                }
            }
        }
        #pragma unroll
        for (int o = 0; o < DOUT; ++o) {
            float v = p[o];
            #pragma unroll
            for (int msk = 32; msk > 0; msk >>= 1) v += __shfl_xor(v, msk, 64);
            p[o] = v;
        }
        #pragma unroll
        for (int o = 0; o < DOUT; ++o) {
            const float cur2 = p[o] + b2r[o];
            const float mo = m2[o];
            const float rs = (mo > 1.0f) ? 1.0f : 0.0f;
            m2[o] = 0.95f * mo + cur2 - rs;
        }
        if (lane < DOUT)
            out[(size_t)t * (BATCH * DOUT) + (size_t)b * DOUT + lane] =
                (m2[lane] > 1.0f) ? 1.0f : 0.0f;
    }
    if (lane < DOUT)
        out[(size_t)T_STEPS * BATCH * DOUT + (size_t)b * DOUT + lane] = m2[lane];
}

// ---------------------------------------------------------------------------
extern "C" void kernel_launch(void* const* d_in, const int* in_sizes, int n_in,
                              void* d_out, int out_size, void* d_ws, size_t ws_size,
                              hipStream_t stream)
{
    const float* x  = (const float*)d_in[0];
    const float* w1 = (const float*)d_in[1];
    const float* b1 = (const float*)d_in[2];
    const float* w2 = (const float*)d_in[3];
    const float* b2 = (const float*)d_in[4];
    float* out = (float*)d_out;

    char* wsb = (char*)d_ws;
    f16*   Ah   = (f16*)(wsb);                                   // 327,680,000 B
    f16*   Wh   = (f16*)(wsb + 327680000);                       //   4,915,200 B
    float* cur1 = (float*)(wsb + 327680000 + 4915200);           // 419,430,400 B
    float* b1p  = (float*)(wsb + 327680000 + 4915200 + 419430400);
    float* w2t  = (float*)(wsb + 327680000 + 4915200 + 419430400 + 4096);

    aconv_kernel<<<4096, 256, 0, stream>>>(x, Ah);
    wconv_kernel<<<1024, 256, 0, stream>>>(w1, b1, w2, Wh, b1p, w2t);
    gemm_kernel<<<1600, 512, 0, stream>>>(Ah, Wh, b1p, cur1);
    phase2_kernel<<<1024, 256, 0, stream>>>(cur1, w2t, b2, out);
}

// Round 7
// 746.715 us; speedup vs baseline: 1.0422x; 1.0339x over previous
//
#include <hip/hip_runtime.h>

typedef _Float16 f16;
typedef _Float16 f16x4 __attribute__((ext_vector_type(4)));
typedef _Float16 f16x8 __attribute__((ext_vector_type(8)));
typedef float f32x4 __attribute__((ext_vector_type(4)));

#define T_STEPS 25
#define BATCH   4096
#define DIN     784
#define DH      1000
#define HP      1024
#define DOUT    10
#define MROWS   (T_STEPS * BATCH)   // 102400
#define KSEG    800                 // 784 padded to 800
#define KA      (2 * KSEG)          // A width: [xhi | xlo] = 1600
#define KB      (3 * KSEG)          // real B width = 2400
#define WROW    2432                // Wh padded width: 38 * 64 (zeros beyond 2400)
#define NT64    38                  // K-tiles of 64

// ---------------------------------------------------------------------------
// Convert X (fp32 [MROWS][784]) -> Ah f16 [MROWS][1600] = [hi(800) | lo(800)]
// ---------------------------------------------------------------------------
__global__ void aconv_kernel(const float* __restrict__ x, f16* __restrict__ Ah)
{
    const int total = MROWS * 200;
    for (int idx = blockIdx.x * blockDim.x + threadIdx.x; idx < total;
         idx += gridDim.x * blockDim.x) {
        const int r  = idx / 200;
        const int c4 = (idx - r * 200) * 4;
        f16x4 hi, lo;
        if (c4 < DIN) {
            const float4 v = *(const float4*)(x + (size_t)r * DIN + c4);
            const float vv[4] = {v.x, v.y, v.z, v.w};
            #pragma unroll
            for (int j = 0; j < 4; ++j) {
                f16 h = (f16)vv[j];
                hi[j] = h;
                lo[j] = (f16)(vv[j] - (float)h);
            }
        } else {
            #pragma unroll
            for (int j = 0; j < 4; ++j) { hi[j] = (f16)0.f; lo[j] = (f16)0.f; }
        }
        *(f16x4*)(Ah + (size_t)r * KA + c4)        = hi;
        *(f16x4*)(Ah + (size_t)r * KA + KSEG + c4) = lo;
    }
}

// ---------------------------------------------------------------------------
// Weights: Wh f16 [HP][2432] = [whi(800) | whi(800) | wlo(800) | 0(32)].
// ---------------------------------------------------------------------------
__global__ void wconv_kernel(const float* __restrict__ w1, const float* __restrict__ b1,
                             const float* __restrict__ w2,
                             f16* __restrict__ Wh, float* __restrict__ b1p,
                             float* __restrict__ w2t)
{
    const int stride = gridDim.x * blockDim.x;
    const int tid0 = blockIdx.x * blockDim.x + threadIdx.x;
    for (int idx = tid0; idx < HP * WROW; idx += stride) {
        const int n  = idx / WROW;
        const int k  = idx - n * WROW;
        f16 v = (f16)0.f;
        if (k < KB) {
            const int seg = k / KSEG;
            const int kc  = k - seg * KSEG;
            float w = (n < DH && kc < DIN) ? w1[n * DIN + kc] : 0.f;
            f16 h = (f16)w;
            v = (seg < 2) ? h : (f16)(w - (float)h);
        }
        Wh[idx] = v;
    }
    for (int idx = tid0; idx < HP; idx += stride)
        b1p[idx] = (idx < DH) ? b1[idx] : 0.f;
    for (int idx = tid0; idx < HP * DOUT; idx += stride) {
        const int h = idx / DOUT;
        const int o = idx - h * DOUT;
        w2t[idx] = (h < DH) ? w2[o * DH + h] : 0.f;
    }
}

// ---------------------------------------------------------------------------
// 256x256-tile GEMM, BK=64, dbuf-2 (128 KB LDS).
// Per K-64 body: 8 stage calls at TOP (covered vmcnt(0) at end), 24 ds_reads
// in two bursts of 12 with counted lgkmcnt(4)/(0), 4 x 16-MFMA sub-phases,
// ONE barrier. 8-chunk XOR swizzle (chunk ^ (row&7)) both-sides.
// K padded 2400->2432 with zero weights: tail products are exact zeros ->
// accumulation bitwise-identical to rounds 3-6 (absmax canary 0.03125).
// Grid: 400 mt x 4 nt = 1600 blocks.
// ---------------------------------------------------------------------------
#define GL(gp, ldsoff) __builtin_amdgcn_global_load_lds( \
    (const __attribute__((address_space(1))) void*)(gp), \
    (__attribute__((address_space(3))) void*)(lds + (ldsoff)), 16, 0, 0)

// Stage K-64 tile tt into buf tt&1: A 4 calls (64 rows x 128 B each) + B 4.
#define STAGE64(tt) do { \
    const int _buf = ((tt) & 1) * 16384; \
    const int _ak  = (((tt) < 25) ? (tt) : ((tt) - 25)) * 64; \
    const int _bk  = (tt) * 64; \
    GL(Ag + _ak + 0 * 64 * KA,   _buf + 0 * 4096 + widoff); \
    GL(Ag + _ak + 1 * 64 * KA,   _buf + 1 * 4096 + widoff); \
    GL(Ag + _ak + 2 * 64 * KA,   _buf + 2 * 4096 + widoff); \
    GL(Ag + _ak + 3 * 64 * KA,   _buf + 3 * 4096 + widoff); \
    GL(Bg + _bk + 0 * 64 * WROW, 32768 + _buf + 0 * 4096 + widoff); \
    GL(Bg + _bk + 1 * 64 * WROW, 32768 + _buf + 1 * 4096 + widoff); \
    GL(Bg + _bk + 2 * 64 * WROW, 32768 + _buf + 2 * 4096 + widoff); \
    GL(Bg + _bk + 3 * 64 * WROW, 32768 + _buf + 3 * 4096 + widoff); } while (0)

#define MFMA16(A0, A1, A2, A3, B0, B1, B2, B3, M0) \
    acc[M0+0][0] = __builtin_amdgcn_mfma_f32_16x16x32_f16(A0, B0, acc[M0+0][0], 0, 0, 0); \
    acc[M0+0][1] = __builtin_amdgcn_mfma_f32_16x16x32_f16(A0, B1, acc[M0+0][1], 0, 0, 0); \
    acc[M0+0][2] = __builtin_amdgcn_mfma_f32_16x16x32_f16(A0, B2, acc[M0+0][2], 0, 0, 0); \
    acc[M0+0][3] = __builtin_amdgcn_mfma_f32_16x16x32_f16(A0, B3, acc[M0+0][3], 0, 0, 0); \
    acc[M0+1][0] = __builtin_amdgcn_mfma_f32_16x16x32_f16(A1, B0, acc[M0+1][0], 0, 0, 0); \
    acc[M0+1][1] = __builtin_amdgcn_mfma_f32_16x16x32_f16(A1, B1, acc[M0+1][1], 0, 0, 0); \
    acc[M0+1][2] = __builtin_amdgcn_mfma_f32_16x16x32_f16(A1, B2, acc[M0+1][2], 0, 0, 0); \
    acc[M0+1][3] = __builtin_amdgcn_mfma_f32_16x16x32_f16(A1, B3, acc[M0+1][3], 0, 0, 0); \
    acc[M0+2][0] = __builtin_amdgcn_mfma_f32_16x16x32_f16(A2, B0, acc[M0+2][0], 0, 0, 0); \
    acc[M0+2][1] = __builtin_amdgcn_mfma_f32_16x16x32_f16(A2, B1, acc[M0+2][1], 0, 0, 0); \
    acc[M0+2][2] = __builtin_amdgcn_mfma_f32_16x16x32_f16(A2, B2, acc[M0+2][2], 0, 0, 0); \
    acc[M0+2][3] = __builtin_amdgcn_mfma_f32_16x16x32_f16(A2, B3, acc[M0+2][3], 0, 0, 0); \
    acc[M0+3][0] = __builtin_amdgcn_mfma_f32_16x16x32_f16(A3, B0, acc[M0+3][0], 0, 0, 0); \
    acc[M0+3][1] = __builtin_amdgcn_mfma_f32_16x16x32_f16(A3, B1, acc[M0+3][1], 0, 0, 0); \
    acc[M0+3][2] = __builtin_amdgcn_mfma_f32_16x16x32_f16(A3, B2, acc[M0+3][2], 0, 0, 0); \
    acc[M0+3][3] = __builtin_amdgcn_mfma_f32_16x16x32_f16(A3, B3, acc[M0+3][3], 0, 0, 0);

#define RD(off) (*(const f16x8*)(lds + (off)))

#define BODY64(tt, STG) do { \
    const int bufc = ((tt) & 1) * 16384; \
    f16x8 b00, b01, b02, b03, a00, a01, a02, a03, a10, a11, a12, a13; \
    f16x8 b10, b11, b12, b13, c00, c01, c02, c03, c10, c11, c12, c13; \
    if (STG) STAGE64((tt) + 1); \
    /* k0 reads: B(4), A-mh0(4), A-mh1(4) */ \
    b00 = RD(bbase + bufc + 0 * 1024 + cA0); \
    b01 = RD(bbase + bufc + 1 * 1024 + cA0); \
    b02 = RD(bbase + bufc + 2 * 1024 + cA0); \
    b03 = RD(bbase + bufc + 3 * 1024 + cA0); \
    a00 = RD(abase + bufc + 0 * 1024 + cA0); \
    a01 = RD(abase + bufc + 1 * 1024 + cA0); \
    a02 = RD(abase + bufc + 2 * 1024 + cA0); \
    a03 = RD(abase + bufc + 3 * 1024 + cA0); \
    a10 = RD(abase + bufc + 4096 + 0 * 1024 + cA0); \
    a11 = RD(abase + bufc + 4096 + 1 * 1024 + cA0); \
    a12 = RD(abase + bufc + 4096 + 2 * 1024 + cA0); \
    a13 = RD(abase + bufc + 4096 + 3 * 1024 + cA0); \
    asm volatile("s_waitcnt lgkmcnt(4)" ::: "memory");  /* b0*,a0* landed */ \
    __builtin_amdgcn_sched_barrier(0); \
    __builtin_amdgcn_s_setprio(1); \
    MFMA16(a00, a01, a02, a03, b00, b01, b02, b03, 0) \
    __builtin_amdgcn_s_setprio(0); \
    asm volatile("s_waitcnt lgkmcnt(0)" ::: "memory");  /* a1* landed */ \
    __builtin_amdgcn_sched_barrier(0); \
    /* k1 reads issued, hidden under s1 MFMA (reg data) */ \
    b10 = RD(bbase + bufc + 0 * 1024 + cA1); \
    b11 = RD(bbase + bufc + 1 * 1024 + cA1); \
    b12 = RD(bbase + bufc + 2 * 1024 + cA1); \
    b13 = RD(bbase + bufc + 3 * 1024 + cA1); \
    c00 = RD(abase + bufc + 0 * 1024 + cA1); \
    c01 = RD(abase + bufc + 1 * 1024 + cA1); \
    c02 = RD(abase + bufc + 2 * 1024 + cA1); \
    c03 = RD(abase + bufc + 3 * 1024 + cA1); \
    c10 = RD(abase + bufc + 4096 + 0 * 1024 + cA1); \
    c11 = RD(abase + bufc + 4096 + 1 * 1024 + cA1); \
    c12 = RD(abase + bufc + 4096 + 2 * 1024 + cA1); \
    c13 = RD(abase + bufc + 4096 + 3 * 1024 + cA1); \
    __builtin_amdgcn_sched_barrier(0); \
    __builtin_amdgcn_s_setprio(1); \
    MFMA16(a10, a11, a12, a13, b00, b01, b02, b03, 4) \
    __builtin_amdgcn_s_setprio(0); \
    asm volatile("s_waitcnt lgkmcnt(4)" ::: "memory");  /* b1*,c0* landed */ \
    __builtin_amdgcn_sched_barrier(0); \
    __builtin_amdgcn_s_setprio(1); \
    MFMA16(c00, c01, c02, c03, b10, b11, b12, b13, 0) \
    __builtin_amdgcn_s_setprio(0); \
    asm volatile("s_waitcnt lgkmcnt(0)" ::: "memory");  /* c1* landed */ \
    __builtin_amdgcn_sched_barrier(0); \
    __builtin_amdgcn_s_setprio(1); \
    MFMA16(c10, c11, c12, c13, b10, b11, b12, b13, 4) \
    __builtin_amdgcn_s_setprio(0); \
    if (STG) { \
        asm volatile("s_waitcnt vmcnt(0)" ::: "memory");  /* covered: issued at body top */ \
        __builtin_amdgcn_s_barrier(); \
    } \
} while (0)

__global__ __launch_bounds__(512, 2)
void gemm_kernel(const f16* __restrict__ A, const f16* __restrict__ B,
                 const float* __restrict__ bias, float* __restrict__ C)
{
    __shared__ f16 lds[65536];   // 128 KB: A dbuf [2][16384] | B dbuf at +32768

    const int bid = blockIdx.x;
    const int swz = (bid & 7) * 200 + (bid >> 3);   // bijective XCD chunking
    const int mt = swz >> 2;
    const int nt = swz & 3;
    const size_t rowBase = (size_t)mt * 256;
    const int colBase = nt * 256;

    const int tid  = threadIdx.x;
    const int wid  = tid >> 6;
    const int lane = tid & 63;
    const int wm = wid >> 2;      // 0..1
    const int wn = wid & 3;       // 0..3

    // staging: thread covers (row = tid>>3, 16B chunk) of a 64-row x 128-B slab;
    // pre-swizzled global chunk g = (tid&7) ^ (row&7)
    const int gsw = (tid & 7) ^ ((tid >> 3) & 7);
    const f16* Ag = A + (rowBase + (tid >> 3)) * KA + gsw * 8;
    const f16* Bg = B + (size_t)(colBase + (tid >> 3)) * WROW + gsw * 8;
    const int widoff = wid * 512;   // wave-uniform LDS base (1 KB/wave)

    // ds_read swizzled chunk constants: chunk = kh*4 + (lane>>4), ^ (row&7)
    const int cA0 = (((lane >> 4))     ^ (lane & 7)) * 8;
    const int cA1 = (((lane >> 4) + 4) ^ (lane & 7)) * 8;
    const int abase = (wm * 128 + (lane & 15)) * 64;
    const int bbase = 32768 + (wn * 64 + (lane & 15)) * 64;

    f32x4 acc[8][4];
    #pragma unroll
    for (int m = 0; m < 8; ++m)
        #pragma unroll
        for (int n = 0; n < 4; ++n)
            acc[m][n] = (f32x4){0.f, 0.f, 0.f, 0.f};

    // prologue: stage tile 0, drain, barrier
    STAGE64(0);
    asm volatile("s_waitcnt vmcnt(0)" ::: "memory");
    __builtin_amdgcn_s_barrier();

    for (int t = 0; t < 36; t += 2) {   // bodies 0..35 (stage t+1)
        BODY64(t, 1);
        BODY64(t + 1, 1);
    }
    BODY64(36, 1);                      // stages tile 37
    BODY64(37, 0);                      // final: no stage, no barrier

    // epilogue: C/D layout col = lane&15, row = (lane>>4)*4 + reg  [m89]
    const int c_col0 = colBase + wn * 64 + (lane & 15);
    const size_t c_row0 = rowBase + wm * 128 + (lane >> 4) * 4;
    #pragma unroll
    for (int n = 0; n < 4; ++n) {
        const int gcol = c_col0 + n * 16;
        const float bv = bias[gcol];
        #pragma unroll
        for (int m = 0; m < 8; ++m) {
            const size_t grow = c_row0 + m * 16;
            #pragma unroll
            for (int r = 0; r < 4; ++r)
                C[(grow + r) * HP + gcol] = acc[m][n][r] + bv;
        }
    }
}

// ---------------------------------------------------------------------------
// Temporal phase: per batch row, all 25 steps, mem1/mem2 in registers.
// ---------------------------------------------------------------------------
__global__ __launch_bounds__(256)
void phase2_kernel(const float* __restrict__ cur1, const float* __restrict__ w2t,
                   const float* __restrict__ b2, float* __restrict__ out)
{
    __shared__ float w2s[HP * DOUT];   // 40 KB
    const int tid = threadIdx.x;
    for (int i = tid; i < HP * DOUT; i += 256) w2s[i] = w2t[i];

    const int lane = tid & 63;
    const int wave = tid >> 6;
    const int b = blockIdx.x * 4 + wave;

    float m1[16];
    #pragma unroll
    for (int i = 0; i < 16; ++i) m1[i] = 0.f;
    float m2[DOUT], b2r[DOUT];
    #pragma unroll
    for (int o = 0; o < DOUT; ++o) { m2[o] = 0.f; b2r[o] = b2[o]; }
    __syncthreads();

    for (int t = 0; t < T_STEPS; ++t) {
        const float* cr = cur1 + ((size_t)t * BATCH + b) * HP;
        float p[DOUT];
        #pragma unroll
        for (int o = 0; o < DOUT; ++o) p[o] = 0.f;

        #pragma unroll
        for (int c = 0; c < 4; ++c) {
            const float4 cu = *(const float4*)(cr + c * 256 + lane * 4);
            const float cv[4] = {cu.x, cu.y, cu.z, cu.w};
            #pragma unroll
            for (int j = 0; j < 4; ++j) {
                const float mo = m1[c * 4 + j];
                const float rs = (mo > 1.0f) ? 1.0f : 0.0f;
                const float mn = 0.95f * mo + cv[j] - rs;
                m1[c * 4 + j] = mn;
                if (mn > 1.0f) {
                    const float* wr = w2s + (c * 256 + lane * 4 + j) * DOUT;
                    #pragma unroll
                    for (int o = 0; o < DOUT; ++o) p[o] += wr[o];
                }
            }
        }
        #pragma unroll
        for (int o = 0; o < DOUT; ++o) {
            float v = p[o];
            #pragma unroll
            for (int msk = 32; msk > 0; msk >>= 1) v += __shfl_xor(v, msk, 64);
            p[o] = v;
        }
        #pragma unroll
        for (int o = 0; o < DOUT; ++o) {
            const float cur2 = p[o] + b2r[o];
            const float mo = m2[o];
            const float rs = (mo > 1.0f) ? 1.0f : 0.0f;
            m2[o] = 0.95f * mo + cur2 - rs;
        }
        if (lane < DOUT)
            out[(size_t)t * (BATCH * DOUT) + (size_t)b * DOUT + lane] =
                (m2[lane] > 1.0f) ? 1.0f : 0.0f;
    }
    if (lane < DOUT)
        out[(size_t)T_STEPS * BATCH * DOUT + (size_t)b * DOUT + lane] = m2[lane];
}

// ---------------------------------------------------------------------------
extern "C" void kernel_launch(void* const* d_in, const int* in_sizes, int n_in,
                              void* d_out, int out_size, void* d_ws, size_t ws_size,
                              hipStream_t stream)
{
    const float* x  = (const float*)d_in[0];
    const float* w1 = (const float*)d_in[1];
    const float* b1 = (const float*)d_in[2];
    const float* w2 = (const float*)d_in[3];
    const float* b2 = (const float*)d_in[4];
    float* out = (float*)d_out;

    char* wsb = (char*)d_ws;
    f16*   Ah   = (f16*)(wsb);                                   // 327,680,000 B
    f16*   Wh   = (f16*)(wsb + 327680000);                       //   4,980,736 B
    float* cur1 = (float*)(wsb + 327680000 + 4980736);           // 419,430,400 B
    float* b1p  = (float*)(wsb + 327680000 + 4980736 + 419430400);
    float* w2t  = (float*)(wsb + 327680000 + 4980736 + 419430400 + 4096);

    aconv_kernel<<<4096, 256, 0, stream>>>(x, Ah);
    wconv_kernel<<<1024, 256, 0, stream>>>(w1, b1, w2, Wh, b1p, w2t);
    gemm_kernel<<<1600, 512, 0, stream>>>(Ah, Wh, b1p, cur1);
    phase2_kernel<<<1024, 256, 0, stream>>>(cur1, w2t, b2, out);
}